// Round 18
// baseline (246.958 us; speedup 1.0000x reference)
//
#include <hip/hip_runtime.h>
#include <math.h>

#define HPIX 256
#define WPIX 256
#define NPIX (HPIX * WPIX)
#define DIM 96
#define QKVC 288
#define NHEAD 8
#define CPH 12
#define EPSN 1e-12f
#define PSTRIDE 544  // per (b,g,chunk) partial record: 256 gqk + 256 gmm + 16 dq + 16 dk

typedef __attribute__((ext_vector_type(8))) short bf16x8;
typedef __attribute__((ext_vector_type(4))) float f32x4;

__device__ __forceinline__ unsigned short f2bf(float f) {
  unsigned u = __float_as_uint(f);
  u += 0x7FFF + ((u >> 16) & 1);  // RNE
  return (unsigned short)(u >> 16);
}
__device__ __forceinline__ float bf2f(unsigned short h) {
  return __uint_as_float((unsigned)h << 16);
}
// HW packed f32x2 -> bf16x2 (RNE), gfx950
__device__ __forceinline__ unsigned pkbf(float a, float b) {
  unsigned r;
  asm("v_cvt_pk_bf16_f32 %0, %1, %2" : "=v"(r) : "v"(a), "v"(b));
  return r;
}
__device__ __forceinline__ bf16x8 pack8(const float* f) {
  union { unsigned u[4]; bf16x8 v; } x;
  x.u[0] = pkbf(f[0], f[1]); x.u[1] = pkbf(f[2], f[3]);
  x.u[2] = pkbf(f[4], f[5]); x.u[3] = pkbf(f[6], f[7]);
  return x.v;
}

// ---------------- K0: weights -> plain bf16 (once per launch) ----------------
__global__ __launch_bounds__(256) void k_wprep(
    const float* __restrict__ wq, const float* __restrict__ wp,
    unsigned short* __restrict__ wqbf, unsigned short* __restrict__ wpbf) {
  int i = blockIdx.x * 256 + threadIdx.x;
  if (i < QKVC * DIM) wqbf[i] = f2bf(wq[i]);
  if (i < DIM * DIM)  wpbf[i] = f2bf(wp[i]);
}

// ---------------- K1/K5: 1x1 conv MFMA GEMM + LDS-transpose epilogue --------
// out[oc][p] = sum_ic w[oc][ic] x[ic][p].  grid (NPIX/PXB, OC/OCB, nb), blk 256.
// PXB=64: xT 16 KB -> 36.4 KB/block -> 4 blocks/CU (phase-overlap theory R18).
template<int OC, int OCB, int PXB, typename InT, typename OutT>
__global__ __launch_bounds__(256, 4) void k_gemm1x1(
    const InT* __restrict__ xin, const unsigned short* __restrict__ wbf,
    OutT* __restrict__ out) {
  constexpr int NJ = PXB / 64;                      // px-groups per wave
  __shared__ __align__(16) unsigned short xT[PXB * 128];  // staging + epilogue scratch
  __shared__ __align__(16) unsigned short wlds[OCB * 104];
  int t = threadIdx.x;
  int p0 = blockIdx.x * PXB;
  int oc0 = blockIdx.y * OCB;
  const InT* xb = xin + (size_t)blockIdx.z * DIM * NPIX;

  // stage W slice: OCB x 96 shorts -> LDS rows padded to 104
  for (int i = t; i < OCB * 12; i += 256) {
    int row = i / 12, seg = i % 12;
    bf16x8 w8 = *(const bf16x8*)(wbf + (size_t)(oc0 + row) * DIM + seg * 8);
    *(bf16x8*)&wlds[row * 104 + seg * 8] = w8;
  }
  // stage X: thread (kg, f4) loads 8 k-rows x 4 px wide, transposes in regs,
  // writes one b128 per px (swizzled unit u = kg ^ swz(px)).
  if (t < 192) {
    int kg = t >> 4;    // 0..11 (8-k group)
    int f4c = t & 15;
    #pragma unroll
    for (int rep = 0; rep < NJ; ++rep) {
      int f4 = f4c + rep * 16;  // 4-px column
      float vals[8][4];
      #pragma unroll
      for (int i = 0; i < 8; ++i) {
        if constexpr (sizeof(InT) == 2) {
          ushort4 v = *(const ushort4*)(xb + (size_t)(kg * 8 + i) * NPIX + p0 + f4 * 4);
          ((ushort*)vals[i])[0] = v.x; ((ushort*)vals[i])[1] = v.y;
          ((ushort*)vals[i])[2] = v.z; ((ushort*)vals[i])[3] = v.w;
        } else {
          float4 v = *(const float4*)(xb + (size_t)(kg * 8 + i) * NPIX + p0 + f4 * 4);
          vals[i][0] = v.x; vals[i][1] = v.y; vals[i][2] = v.z; vals[i][3] = v.w;
        }
      }
      #pragma unroll
      for (int c = 0; c < 4; ++c) {
        int px = f4 * 4 + c;
        int u = kg ^ ((px & 7) ^ ((px >> 3) & 7));
        bf16x8 hv;
        if constexpr (sizeof(InT) == 2) {
          #pragma unroll
          for (int i = 0; i < 8; ++i) hv[i] = (short)((ushort*)vals[i])[c];
        } else {
          float col[8];
          #pragma unroll
          for (int i = 0; i < 8; ++i) col[i] = vals[i][c];
          hv = pack8(col);
        }
        *(bf16x8*)&xT[px * 128 + u * 8] = hv;
      }
    }
  }
  __syncthreads();

  int lane = t & 63, wv = t >> 6;
  int r16 = lane & 15, kg8 = lane >> 4;

  // X fragments from LDS: NJ px-groups x 3 k-steps
  bf16x8 bfr[3][NJ];
  #pragma unroll
  for (int nj = 0; nj < NJ; ++nj) {
    int px = wv * (16 * NJ) + nj * 16 + r16;
    int swz = (px & 7) ^ ((px >> 3) & 7);
    #pragma unroll
    for (int ks = 0; ks < 3; ++ks) {
      int u = (ks * 4 + kg8) ^ swz;
      bfr[ks][nj] = *(const bf16x8*)&xT[px * 128 + u * 8];
    }
  }

  f32x4 acc[OCB / 16][NJ];
  #pragma unroll
  for (int mi = 0; mi < OCB / 16; ++mi)
    #pragma unroll
    for (int nj = 0; nj < NJ; ++nj) acc[mi][nj] = (f32x4){0.f, 0.f, 0.f, 0.f};

  #pragma unroll
  for (int mi = 0; mi < OCB / 16; ++mi) {
    #pragma unroll
    for (int ks = 0; ks < 3; ++ks) {
      bf16x8 a = *(const bf16x8*)&wlds[(mi * 16 + r16) * 104 + ks * 32 + kg8 * 8];
      #pragma unroll
      for (int nj = 0; nj < NJ; ++nj)
        acc[mi][nj] = __builtin_amdgcn_mfma_f32_16x16x32_bf16(a, bfr[ks][nj], acc[mi][nj], 0, 0, 0);
    }
  }

  // ---- epilogue: LDS transpose -> wide coalesced stores ----
  // acc layout (R9-verified): oc = oc0+mi*16+kg8*4+j, px = wv*16*NJ+nj*16+r16
  OutT* op = out + (size_t)blockIdx.z * OC * NPIX + p0;
  __syncthreads();  // xT fragments consumed; reuse as transpose scratch
  if constexpr (sizeof(OutT) == 2) {
    unsigned short* tl = xT;  // [OCB][PXB+8] shorts
    #pragma unroll
    for (int mi = 0; mi < OCB / 16; ++mi)
      #pragma unroll
      for (int nj = 0; nj < NJ; ++nj)
        #pragma unroll
        for (int j = 0; j < 4; ++j)
          tl[(mi * 16 + kg8 * 4 + j) * (PXB + 8) + wv * (16 * NJ) + nj * 16 + r16]
              = f2bf(acc[mi][nj][j]);
    __syncthreads();
    constexpr int SEGS = PXB / 8;                 // b128 segs per oc
    #pragma unroll
    for (int r = 0; r < OCB * SEGS / 256; ++r) {
      int idx = t + 256 * r;
      int oc = idx / SEGS, seg = idx % SEGS;
      bf16x8 v8 = *(const bf16x8*)&tl[oc * (PXB + 8) + seg * 8];
      *(bf16x8*)(op + (size_t)(oc0 + oc) * NPIX + seg * 8) = v8;
    }
  } else {
    float* tl = (float*)xT;  // [OCB/2][PXB+8] floats per half
    #pragma unroll
    for (int half = 0; half < 2; ++half) {
      if (half) __syncthreads();
      #pragma unroll
      for (int mi = half * (OCB / 32); mi < (half + 1) * (OCB / 32); ++mi)
        #pragma unroll
        for (int nj = 0; nj < NJ; ++nj)
          #pragma unroll
          for (int j = 0; j < 4; ++j)
            tl[(mi * 16 + kg8 * 4 + j - half * (OCB / 2)) * (PXB + 8)
               + wv * (16 * NJ) + nj * 16 + r16] = acc[mi][nj][j];
      __syncthreads();
      constexpr int SEGS = PXB / 4;               // float4 segs per oc
      #pragma unroll
      for (int r = 0; r < (OCB / 2) * SEGS / 256; ++r) {
        int idx = t + 256 * r;
        int oc = idx / SEGS, seg = idx % SEGS;
        float4 v4 = *(const float4*)&tl[oc * (PXB + 8) + seg * 4];
        *(float4*)(op + (size_t)(oc0 + half * (OCB / 2) + oc) * NPIX + seg * 4) = v4;
      }
    }
  }
}

// ---------------- K2: depthwise 3x3 bf16, 8 px x 2 rows per thread ----------
// grid (NPIX/4096, 288, nb), block 256. ch<192 -> qk planes; ch>=192 -> v.
__global__ __launch_bounds__(256) void k_dw3x3_bf(
    const unsigned short* __restrict__ in, const float* __restrict__ w,
    unsigned short* __restrict__ qkout, unsigned short* __restrict__ vout) {
  int t = threadIdx.x;
  int xg = t & 31, yp = t >> 5;
  int y0 = blockIdx.x * 16 + yp * 2;
  int x0 = xg * 8;
  int ch = blockIdx.y, b = blockIdx.z;
  const unsigned short* plane = in + ((size_t)b * QKVC + ch) * NPIX;
  const float* wc = w + ch * 9;

  float accA[8], accB[8];
  #pragma unroll
  for (int j = 0; j < 8; ++j) { accA[j] = 0.f; accB[j] = 0.f; }

  #pragma unroll
  for (int r = 0; r < 4; ++r) {
    int yy = y0 - 1 + r;
    float f[8];
    if (yy >= 0 && yy < HPIX) {
      bf16x8 v8 = *(const bf16x8*)(plane + (size_t)yy * WPIX + x0);
      #pragma unroll
      for (int j = 0; j < 8; ++j) f[j] = bf2f((unsigned short)v8[j]);
    } else {
      #pragma unroll
      for (int j = 0; j < 8; ++j) f[j] = 0.f;
    }
    float l = __shfl_up(f[7], 1);
    float rr = __shfl_down(f[0], 1);
    if (x0 == 0) l = 0.f;
    if (x0 == 248) rr = 0.f;
    if (r < 3) {
      float w0 = wc[r * 3], w1 = wc[r * 3 + 1], w2 = wc[r * 3 + 2];
      accA[0] = fmaf(w0, l, fmaf(w1, f[0], fmaf(w2, f[1], accA[0])));
      #pragma unroll
      for (int j = 1; j < 7; ++j)
        accA[j] = fmaf(w0, f[j - 1], fmaf(w1, f[j], fmaf(w2, f[j + 1], accA[j])));
      accA[7] = fmaf(w0, f[6], fmaf(w1, f[7], fmaf(w2, rr, accA[7])));
    }
    if (r > 0) {
      float w0 = wc[(r - 1) * 3], w1 = wc[(r - 1) * 3 + 1], w2 = wc[(r - 1) * 3 + 2];
      accB[0] = fmaf(w0, l, fmaf(w1, f[0], fmaf(w2, f[1], accB[0])));
      #pragma unroll
      for (int j = 1; j < 7; ++j)
        accB[j] = fmaf(w0, f[j - 1], fmaf(w1, f[j], fmaf(w2, f[j + 1], accB[j])));
      accB[7] = fmaf(w0, f[6], fmaf(w1, f[7], fmaf(w2, rr, accB[7])));
    }
  }

  bf16x8 oA = pack8(accA), oB = pack8(accB);
  size_t pA = (size_t)y0 * WPIX + x0;
  unsigned short* outp;
  if (ch < 192) outp = qkout + ((size_t)b * 192 + ch) * NPIX;
  else          outp = vout + ((size_t)b * DIM + ch - 192) * NPIX;
  *(bf16x8*)(outp + pA) = oA;
  *(bf16x8*)(outp + pA + WPIX) = oB;
}

// ---------------- K3a: MFMA partial grams + row norms, 1 wave/block ----------
// grid (96, 16, nb), block 64. Wave covers s in [cb*256, cb*256+256).
__global__ __launch_bounds__(64) void k_attn_part(
    const unsigned short* __restrict__ qkbuf, const float* __restrict__ mask,
    float* __restrict__ pbuf) {
  int g = blockIdx.x, cb = blockIdx.y, lb = blockIdx.z;
  int lane = threadIdx.x;
  int r16 = lane & 15, kg8 = lane >> 4;

  const unsigned short* qb = qkbuf + ((size_t)lb * 192 + g) * NPIX;
  const unsigned short* kb = qkbuf + ((size_t)lb * 192 + 96 + g) * NPIX;
  const float* mb = mask + ((size_t)lb * DIM + g) * NPIX;

  int rbase = ((r16 >> 2) << 6) * WPIX + ((r16 & 3) << 6);

  f32x4 aqk = {0.f, 0.f, 0.f, 0.f}, amm = {0.f, 0.f, 0.f, 0.f};
  float dq = 0.f, dk = 0.f;

  #pragma unroll
  for (int ks = 0; ks < 8; ++ks) {
    int s = cb * 256 + ks * 32 + kg8 * 8;
    int off = rbase + (s >> 6) * WPIX + (s & 63);
    bf16x8 qf = *(const bf16x8*)(qb + off);
    bf16x8 kf = *(const bf16x8*)(kb + off);
    float4 m0 = *(const float4*)(mb + off);
    float4 m1 = *(const float4*)(mb + off + 4);
    union { unsigned u[4]; bf16x8 v; } mm_;
    mm_.u[0] = pkbf(m0.x, m0.y); mm_.u[1] = pkbf(m0.z, m0.w);
    mm_.u[2] = pkbf(m1.x, m1.y); mm_.u[3] = pkbf(m1.z, m1.w);
    bf16x8 mf = mm_.v;
    aqk = __builtin_amdgcn_mfma_f32_16x16x32_bf16(qf, kf, aqk, 0, 0, 0);
    amm = __builtin_amdgcn_mfma_f32_16x16x32_bf16(mf, mf, amm, 0, 0, 0);
    #pragma unroll
    for (int i = 0; i < 8; ++i) {
      float qv = bf2f((unsigned short)qf[i]); dq = fmaf(qv, qv, dq);
      float kv = bf2f((unsigned short)kf[i]); dk = fmaf(kv, kv, dk);
    }
  }
  dq += __shfl_xor(dq, 16); dq += __shfl_xor(dq, 32);
  dk += __shfl_xor(dk, 16); dk += __shfl_xor(dk, 32);

  float* pb = pbuf + (((size_t)lb * DIM + g) * 16 + cb) * PSTRIDE;
  #pragma unroll
  for (int j = 0; j < 4; ++j) {
    int n = kg8 * 4 + j;
    pb[n * 16 + r16] = aqk[j];
    pb[256 + n * 16 + r16] = amm[j];
  }
  if (lane < 16) { pb[512 + r16] = dq; pb[528 + r16] = dk; }
}

// ---------------- K3b: reduce partials + softmax chain -> attn[16][16] -------
// grid (96, nb), block 256
__global__ __launch_bounds__(256) void k_attn_fin(
    const float* __restrict__ pbuf, const float* __restrict__ tx,
    const float* __restrict__ tm, float* __restrict__ attnbuf) {
  int g = blockIdx.x;
  int lb = blockIdx.y;
  int h = g / CPH;
  int t = threadIdx.x;
  int n = t >> 4, m = t & 15;

  const float* pb = pbuf + ((size_t)lb * DIM + g) * 16 * PSTRIDE;
  float gqk = 0.f, gmm = 0.f, dq = 0.f, dk = 0.f;
  #pragma unroll
  for (int c = 0; c < 16; ++c) {
    const float* p = pb + c * PSTRIDE;
    gqk += p[t];
    gmm += p[256 + t];
    dq  += p[512 + n];
    dk  += p[528 + m];
  }

  float qn = fmaxf(sqrtf(dq), EPSN);
  float km = fmaxf(sqrtf(dk), EPSN);

  float ax = gqk / (qn * km) * tx[h];
  float r0 = ax;
  #pragma unroll
  for (int off = 8; off; off >>= 1) r0 = fmaxf(r0, __shfl_xor(r0, off, 16));
  float e0 = expf(ax - r0), es0 = e0;
  #pragma unroll
  for (int off = 8; off; off >>= 1) es0 += __shfl_xor(es0, off, 16);
  float attx = e0 / es0;

  float am = gmm * tm[h];
  float s2 = am * am;
  #pragma unroll
  for (int off = 8; off; off >>= 1) s2 += __shfl_xor(s2, off, 16);
  am = am / fmaxf(sqrtf(s2), EPSN);
  float r1 = am;
  #pragma unroll
  for (int off = 8; off; off >>= 1) r1 = fmaxf(r1, __shfl_xor(r1, off, 16));
  float e1 = expf(am - r1), es1 = e1;
  #pragma unroll
  for (int off = 8; off; off >>= 1) es1 += __shfl_xor(es1, off, 16);
  float attm = e1 / es1;

  float aa = attx + attm;
  float r2 = aa;
  #pragma unroll
  for (int off = 8; off; off >>= 1) r2 = fmaxf(r2, __shfl_xor(r2, off, 16));
  float e2 = expf(aa - r2), es2 = e2;
  #pragma unroll
  for (int off = 8; off; off >>= 1) es2 += __shfl_xor(es2, off, 16);

  attnbuf[(((size_t)lb * DIM + g) << 8) + t] = e2 / es2;
}

// ---------------- K4: out_blk = attn @ v (bf16), t written bf16 --------------
// grid (64 (hh), 96 (g), nb), block 256
__global__ __launch_bounds__(256) void k_pv(
    const unsigned short* __restrict__ vbuf, const float* __restrict__ attnbuf,
    unsigned short* __restrict__ tout) {
  int hh = blockIdx.x;
  int g = blockIdx.y;
  int lb = blockIdx.z;
  int t = threadIdx.x;
  int ww = t & 63, grp = t >> 6;

  __shared__ float vt[16][64];
  __shared__ float at[16][16];

  const unsigned short* vb = vbuf + ((size_t)lb * DIM + g) * NPIX;
  #pragma unroll
  for (int jj = 0; jj < 4; ++jj) {
    int mm = jj * 4 + grp;
    vt[mm][ww] = bf2f(vb[(size_t)(((mm >> 2) << 6) + hh) * WPIX + ((mm & 3) << 6) + ww]);
  }
  at[t >> 4][t & 15] = attnbuf[(((size_t)lb * DIM + g) << 8) + t];
  __syncthreads();

  unsigned short* ob = tout + ((size_t)lb * DIM + g) * NPIX;
  #pragma unroll
  for (int jj = 0; jj < 4; ++jj) {
    int nn = jj * 4 + grp;
    float acc = 0.f;
    #pragma unroll
    for (int mm = 0; mm < 16; ++mm)
      acc = fmaf(at[nn][mm], vt[mm][ww], acc);
    ob[(size_t)(((nn >> 2) << 6) + hh) * WPIX + ((nn & 3) << 6) + ww] = f2bf(acc);
  }
}

extern "C" void kernel_launch(void* const* d_in, const int* in_sizes, int n_in,
                              void* d_out, int out_size, void* d_ws, size_t ws_size,
                              hipStream_t stream) {
  const float* x      = (const float*)d_in[0];
  const float* mask   = (const float*)d_in[1];
  const float* w_qkv  = (const float*)d_in[2];
  const float* w_dw   = (const float*)d_in[3];
  const float* w_proj = (const float*)d_in[4];
  const float* tx     = (const float*)d_in[5];
  const float* tm     = (const float*)d_in[6];
  float* out = (float*)d_out;

  const size_t wB     = (size_t)(QKVC * DIM + DIM * DIM) * 2;  // 73728
  const size_t qkv1B  = (size_t)QKVC * NPIX * 2;   // 37.75 MB (>= tbuf 12.6 MB bf16)
  const size_t qkB    = (size_t)192 * NPIX * 2;    // 25.2 MB
  const size_t vB     = (size_t)DIM * NPIX * 2;    // 12.6 MB
  const size_t atB    = (size_t)DIM * 256 * 4;
  const size_t pbB    = (size_t)DIM * 16 * PSTRIDE * 4;
  const size_t perB   = qkv1B + qkB + vB + atB + pbB;

  int nb = (ws_size >= wB + 4 * perB) ? 4 : 1;
  int npass = 4 / nb;

  char* base = (char*)d_ws;
  unsigned short* wqbf = (unsigned short*)base;
  unsigned short* wpbf = wqbf + QKVC * DIM;
  char* p = base + wB;
  unsigned short* qkv1bf = (unsigned short*)p;  p += (size_t)nb * qkv1B;
  unsigned short* tbuf   = qkv1bf;              // alias: dead after dw
  unsigned short* qkbuf  = (unsigned short*)p;  p += (size_t)nb * qkB;
  unsigned short* vbuf   = (unsigned short*)p;  p += (size_t)nb * vB;
  float*          attn   = (float*)p;           p += (size_t)nb * atB;
  float*          pbuf   = (float*)p;

  dim3 blk(256);
  k_wprep<<<dim3((QKVC * DIM + 255) / 256), blk, 0, stream>>>(
      w_qkv, w_proj, wqbf, wpbf);

  for (int pass = 0; pass < npass; ++pass) {
    int b0 = pass * nb;
    k_gemm1x1<QKVC, 96, 64, float, unsigned short><<<dim3(NPIX / 64, 3, nb), blk, 0, stream>>>(
        x + (size_t)b0 * DIM * NPIX, wqbf, qkv1bf);
    k_dw3x3_bf<<<dim3(NPIX / 4096, QKVC, nb), blk, 0, stream>>>(
        qkv1bf, w_dw, qkbuf, vbuf);
    k_attn_part<<<dim3(DIM, 16, nb), dim3(64), 0, stream>>>(
        qkbuf, mask + (size_t)b0 * DIM * NPIX, pbuf);
    k_attn_fin<<<dim3(DIM, nb), blk, 0, stream>>>(pbuf, tx, tm, attn);
    k_pv<<<dim3(64, DIM, nb), blk, 0, stream>>>(vbuf, attn, tbuf);
    k_gemm1x1<DIM, 96, 64, unsigned short, float><<<dim3(NPIX / 64, 1, nb), blk, 0, stream>>>(
        tbuf, wpbf, out + (size_t)b0 * DIM * NPIX);
  }
}

// Round 19
// 239.156 us; speedup vs baseline: 1.0326x; 1.0326x over previous
//
#include <hip/hip_runtime.h>
#include <math.h>

#define HPIX 256
#define WPIX 256
#define NPIX (HPIX * WPIX)
#define DIM 96
#define QKVC 288
#define NHEAD 8
#define CPH 12
#define EPSN 1e-12f
#define PSTRIDE 544  // per (b,g,chunk) partial record: 256 gqk + 256 gmm + 16 dq + 16 dk

typedef __attribute__((ext_vector_type(8))) short bf16x8;
typedef __attribute__((ext_vector_type(4))) float f32x4;

__device__ __forceinline__ unsigned short f2bf(float f) {
  unsigned u = __float_as_uint(f);
  u += 0x7FFF + ((u >> 16) & 1);  // RNE
  return (unsigned short)(u >> 16);
}
__device__ __forceinline__ float bf2f(unsigned short h) {
  return __uint_as_float((unsigned)h << 16);
}
// HW packed f32x2 -> bf16x2 (RNE), gfx950
__device__ __forceinline__ unsigned pkbf(float a, float b) {
  unsigned r;
  asm("v_cvt_pk_bf16_f32 %0, %1, %2" : "=v"(r) : "v"(a), "v"(b));
  return r;
}
__device__ __forceinline__ bf16x8 pack8(const float* f) {
  union { unsigned u[4]; bf16x8 v; } x;
  x.u[0] = pkbf(f[0], f[1]); x.u[1] = pkbf(f[2], f[3]);
  x.u[2] = pkbf(f[4], f[5]); x.u[3] = pkbf(f[6], f[7]);
  return x.v;
}

// ---------------- K0: weights -> plain bf16 (once per launch) ----------------
__global__ __launch_bounds__(256) void k_wprep(
    const float* __restrict__ wq, const float* __restrict__ wp,
    unsigned short* __restrict__ wqbf, unsigned short* __restrict__ wpbf) {
  int i = blockIdx.x * 256 + threadIdx.x;
  if (i < QKVC * DIM) wqbf[i] = f2bf(wq[i]);
  if (i < DIM * DIM)  wpbf[i] = f2bf(wp[i]);
}

// ---------------- K1/K5: 1x1 conv MFMA GEMM + LDS-transpose epilogue --------
// out[oc][p] = sum_ic w[oc][ic] x[ic][p].  grid (NPIX/128, OC/OCB, nb), blk 256.
// OCB=96, PXB=128 (R17-measured best configuration).
template<int OC, int OCB, typename InT, typename OutT>
__global__ __launch_bounds__(256, 3) void k_gemm1x1(
    const InT* __restrict__ xin, const unsigned short* __restrict__ wbf,
    OutT* __restrict__ out) {
  __shared__ __align__(16) unsigned short xT[128 * 128];    // staging + epilogue scratch
  __shared__ __align__(16) unsigned short wlds[OCB * 104];
  int t = threadIdx.x;
  int p0 = blockIdx.x * 128;
  int oc0 = blockIdx.y * OCB;
  const InT* xb = xin + (size_t)blockIdx.z * DIM * NPIX;

  // stage W slice: OCB x 96 shorts -> LDS rows padded to 104
  for (int i = t; i < OCB * 12; i += 256) {
    int row = i / 12, seg = i % 12;
    bf16x8 w8 = *(const bf16x8*)(wbf + (size_t)(oc0 + row) * DIM + seg * 8);
    *(bf16x8*)&wlds[row * 104 + seg * 8] = w8;
  }
  // stage X: thread (kg, f4) loads 8 k-rows x 4 px wide, transposes in regs,
  // writes one b128 per px (swizzled unit u = kg ^ swz(px)).
  if (t < 192) {
    int kg = t >> 4;    // 0..11 (8-k group)
    int f4c = t & 15;
    #pragma unroll
    for (int rep = 0; rep < 2; ++rep) {
      int f4 = f4c + rep * 16;  // 4-px column 0..31
      float vals[8][4];
      #pragma unroll
      for (int i = 0; i < 8; ++i) {
        if constexpr (sizeof(InT) == 2) {
          ushort4 v = *(const ushort4*)(xb + (size_t)(kg * 8 + i) * NPIX + p0 + f4 * 4);
          ((ushort*)vals[i])[0] = v.x; ((ushort*)vals[i])[1] = v.y;
          ((ushort*)vals[i])[2] = v.z; ((ushort*)vals[i])[3] = v.w;
        } else {
          float4 v = *(const float4*)(xb + (size_t)(kg * 8 + i) * NPIX + p0 + f4 * 4);
          vals[i][0] = v.x; vals[i][1] = v.y; vals[i][2] = v.z; vals[i][3] = v.w;
        }
      }
      #pragma unroll
      for (int c = 0; c < 4; ++c) {
        int px = f4 * 4 + c;
        int u = kg ^ ((px & 7) ^ ((px >> 3) & 7));
        bf16x8 hv;
        if constexpr (sizeof(InT) == 2) {
          #pragma unroll
          for (int i = 0; i < 8; ++i) hv[i] = (short)((ushort*)vals[i])[c];
        } else {
          float col[8];
          #pragma unroll
          for (int i = 0; i < 8; ++i) col[i] = vals[i][c];
          hv = pack8(col);
        }
        *(bf16x8*)&xT[px * 128 + u * 8] = hv;
      }
    }
  }
  __syncthreads();

  int lane = t & 63, wv = t >> 6;
  int r16 = lane & 15, kg8 = lane >> 4;

  // X fragments from LDS: 2 px-groups x 3 k-steps
  bf16x8 bfr[3][2];
  #pragma unroll
  for (int nj = 0; nj < 2; ++nj) {
    int px = wv * 32 + nj * 16 + r16;
    int swz = (px & 7) ^ ((px >> 3) & 7);
    #pragma unroll
    for (int ks = 0; ks < 3; ++ks) {
      int u = (ks * 4 + kg8) ^ swz;
      bfr[ks][nj] = *(const bf16x8*)&xT[px * 128 + u * 8];
    }
  }

  f32x4 acc[OCB / 16][2];
  #pragma unroll
  for (int mi = 0; mi < OCB / 16; ++mi)
    #pragma unroll
    for (int nj = 0; nj < 2; ++nj) acc[mi][nj] = (f32x4){0.f, 0.f, 0.f, 0.f};

  #pragma unroll
  for (int mi = 0; mi < OCB / 16; ++mi) {
    #pragma unroll
    for (int ks = 0; ks < 3; ++ks) {
      bf16x8 a = *(const bf16x8*)&wlds[(mi * 16 + r16) * 104 + ks * 32 + kg8 * 8];
      #pragma unroll
      for (int nj = 0; nj < 2; ++nj)
        acc[mi][nj] = __builtin_amdgcn_mfma_f32_16x16x32_bf16(a, bfr[ks][nj], acc[mi][nj], 0, 0, 0);
    }
  }

  // ---- epilogue: LDS transpose -> wide coalesced stores ----
  // acc layout (R9-verified): oc = oc0+mi*16+kg8*4+j, px = wv*32+nj*16+r16
  OutT* op = out + (size_t)blockIdx.z * OC * NPIX + p0;
  __syncthreads();  // xT fragments consumed; reuse as transpose scratch
  if constexpr (sizeof(OutT) == 2) {
    unsigned short* tl = xT;  // [OCB][136] shorts
    #pragma unroll
    for (int mi = 0; mi < OCB / 16; ++mi)
      #pragma unroll
      for (int nj = 0; nj < 2; ++nj)
        #pragma unroll
        for (int j = 0; j < 4; ++j)
          tl[(mi * 16 + kg8 * 4 + j) * 136 + wv * 32 + nj * 16 + r16] = f2bf(acc[mi][nj][j]);
    __syncthreads();
    #pragma unroll
    for (int r = 0; r < OCB / 16; ++r) {         // OCB*16 b128 segs total
      int idx = t + 256 * r;
      int oc = idx >> 4, seg = idx & 15;         // 16 8-px segs per oc
      bf16x8 v8 = *(const bf16x8*)&tl[oc * 136 + seg * 8];
      *(bf16x8*)(op + (size_t)(oc0 + oc) * NPIX + seg * 8) = v8;
    }
  } else {
    float* tl = (float*)xT;  // [OCB/2][136] floats per half
    #pragma unroll
    for (int half = 0; half < 2; ++half) {
      if (half) __syncthreads();
      #pragma unroll
      for (int mi = half * (OCB / 32); mi < (half + 1) * (OCB / 32); ++mi)
        #pragma unroll
        for (int nj = 0; nj < 2; ++nj)
          #pragma unroll
          for (int j = 0; j < 4; ++j)
            tl[(mi * 16 + kg8 * 4 + j - half * (OCB / 2)) * 136 + wv * 32 + nj * 16 + r16]
                = acc[mi][nj][j];
      __syncthreads();
      #pragma unroll
      for (int r = 0; r < OCB / 16; ++r) {       // (OCB/2)*32 f4 segs per half
        int idx = t + 256 * r;
        int oc = idx >> 5, seg = idx & 31;       // 32 4-px segs per oc
        float4 v4 = *(const float4*)&tl[oc * 136 + seg * 4];
        *(float4*)(op + (size_t)(oc0 + half * (OCB / 2) + oc) * NPIX + seg * 4) = v4;
      }
    }
  }
}

// ---------------- K2: depthwise 3x3 bf16, 8 px x 2 rows per thread ----------
// grid (NPIX/4096, 288, nb), block 256. ch<192 -> qk planes; ch>=192 -> v.
__global__ __launch_bounds__(256) void k_dw3x3_bf(
    const unsigned short* __restrict__ in, const float* __restrict__ w,
    unsigned short* __restrict__ qkout, unsigned short* __restrict__ vout) {
  int t = threadIdx.x;
  int xg = t & 31, yp = t >> 5;
  int y0 = blockIdx.x * 16 + yp * 2;
  int x0 = xg * 8;
  int ch = blockIdx.y, b = blockIdx.z;
  const unsigned short* plane = in + ((size_t)b * QKVC + ch) * NPIX;
  const float* wc = w + ch * 9;

  float accA[8], accB[8];
  #pragma unroll
  for (int j = 0; j < 8; ++j) { accA[j] = 0.f; accB[j] = 0.f; }

  #pragma unroll
  for (int r = 0; r < 4; ++r) {
    int yy = y0 - 1 + r;
    float f[8];
    if (yy >= 0 && yy < HPIX) {
      bf16x8 v8 = *(const bf16x8*)(plane + (size_t)yy * WPIX + x0);
      #pragma unroll
      for (int j = 0; j < 8; ++j) f[j] = bf2f((unsigned short)v8[j]);
    } else {
      #pragma unroll
      for (int j = 0; j < 8; ++j) f[j] = 0.f;
    }
    float l = __shfl_up(f[7], 1);
    float rr = __shfl_down(f[0], 1);
    if (x0 == 0) l = 0.f;
    if (x0 == 248) rr = 0.f;
    if (r < 3) {
      float w0 = wc[r * 3], w1 = wc[r * 3 + 1], w2 = wc[r * 3 + 2];
      accA[0] = fmaf(w0, l, fmaf(w1, f[0], fmaf(w2, f[1], accA[0])));
      #pragma unroll
      for (int j = 1; j < 7; ++j)
        accA[j] = fmaf(w0, f[j - 1], fmaf(w1, f[j], fmaf(w2, f[j + 1], accA[j])));
      accA[7] = fmaf(w0, f[6], fmaf(w1, f[7], fmaf(w2, rr, accA[7])));
    }
    if (r > 0) {
      float w0 = wc[(r - 1) * 3], w1 = wc[(r - 1) * 3 + 1], w2 = wc[(r - 1) * 3 + 2];
      accB[0] = fmaf(w0, l, fmaf(w1, f[0], fmaf(w2, f[1], accB[0])));
      #pragma unroll
      for (int j = 1; j < 7; ++j)
        accB[j] = fmaf(w0, f[j - 1], fmaf(w1, f[j], fmaf(w2, f[j + 1], accB[j])));
      accB[7] = fmaf(w0, f[6], fmaf(w1, f[7], fmaf(w2, rr, accB[7])));
    }
  }

  bf16x8 oA = pack8(accA), oB = pack8(accB);
  size_t pA = (size_t)y0 * WPIX + x0;
  unsigned short* outp;
  if (ch < 192) outp = qkout + ((size_t)b * 192 + ch) * NPIX;
  else          outp = vout + ((size_t)b * DIM + ch - 192) * NPIX;
  *(bf16x8*)(outp + pA) = oA;
  *(bf16x8*)(outp + pA + WPIX) = oB;
}

// ---------------- K3a: MFMA partial grams + row norms, 1 wave/block ----------
// grid (96, 16, nb), block 64. Wave covers s in [cb*256, cb*256+256).
__global__ __launch_bounds__(64) void k_attn_part(
    const unsigned short* __restrict__ qkbuf, const float* __restrict__ mask,
    float* __restrict__ pbuf) {
  int g = blockIdx.x, cb = blockIdx.y, lb = blockIdx.z;
  int lane = threadIdx.x;
  int r16 = lane & 15, kg8 = lane >> 4;

  const unsigned short* qb = qkbuf + ((size_t)lb * 192 + g) * NPIX;
  const unsigned short* kb = qkbuf + ((size_t)lb * 192 + 96 + g) * NPIX;
  const float* mb = mask + ((size_t)lb * DIM + g) * NPIX;

  int rbase = ((r16 >> 2) << 6) * WPIX + ((r16 & 3) << 6);

  f32x4 aqk = {0.f, 0.f, 0.f, 0.f}, amm = {0.f, 0.f, 0.f, 0.f};
  float dq = 0.f, dk = 0.f;

  #pragma unroll
  for (int ks = 0; ks < 8; ++ks) {
    int s = cb * 256 + ks * 32 + kg8 * 8;
    int off = rbase + (s >> 6) * WPIX + (s & 63);
    bf16x8 qf = *(const bf16x8*)(qb + off);
    bf16x8 kf = *(const bf16x8*)(kb + off);
    float4 m0 = *(const float4*)(mb + off);
    float4 m1 = *(const float4*)(mb + off + 4);
    union { unsigned u[4]; bf16x8 v; } mm_;
    mm_.u[0] = pkbf(m0.x, m0.y); mm_.u[1] = pkbf(m0.z, m0.w);
    mm_.u[2] = pkbf(m1.x, m1.y); mm_.u[3] = pkbf(m1.z, m1.w);
    bf16x8 mf = mm_.v;
    aqk = __builtin_amdgcn_mfma_f32_16x16x32_bf16(qf, kf, aqk, 0, 0, 0);
    amm = __builtin_amdgcn_mfma_f32_16x16x32_bf16(mf, mf, amm, 0, 0, 0);
    #pragma unroll
    for (int i = 0; i < 8; ++i) {
      float qv = bf2f((unsigned short)qf[i]); dq = fmaf(qv, qv, dq);
      float kv = bf2f((unsigned short)kf[i]); dk = fmaf(kv, kv, dk);
    }
  }
  dq += __shfl_xor(dq, 16); dq += __shfl_xor(dq, 32);
  dk += __shfl_xor(dk, 16); dk += __shfl_xor(dk, 32);

  float* pb = pbuf + (((size_t)lb * DIM + g) * 16 + cb) * PSTRIDE;
  #pragma unroll
  for (int j = 0; j < 4; ++j) {
    int n = kg8 * 4 + j;
    pb[n * 16 + r16] = aqk[j];
    pb[256 + n * 16 + r16] = amm[j];
  }
  if (lane < 16) { pb[512 + r16] = dq; pb[528 + r16] = dk; }
}

// ---------------- K3b: reduce partials + softmax chain -> attn[16][16] -------
// grid (96, nb), block 256
__global__ __launch_bounds__(256) void k_attn_fin(
    const float* __restrict__ pbuf, const float* __restrict__ tx,
    const float* __restrict__ tm, float* __restrict__ attnbuf) {
  int g = blockIdx.x;
  int lb = blockIdx.y;
  int h = g / CPH;
  int t = threadIdx.x;
  int n = t >> 4, m = t & 15;

  const float* pb = pbuf + ((size_t)lb * DIM + g) * 16 * PSTRIDE;
  float gqk = 0.f, gmm = 0.f, dq = 0.f, dk = 0.f;
  #pragma unroll
  for (int c = 0; c < 16; ++c) {
    const float* p = pb + c * PSTRIDE;
    gqk += p[t];
    gmm += p[256 + t];
    dq  += p[512 + n];
    dk  += p[528 + m];
  }

  float qn = fmaxf(sqrtf(dq), EPSN);
  float km = fmaxf(sqrtf(dk), EPSN);

  float ax = gqk / (qn * km) * tx[h];
  float r0 = ax;
  #pragma unroll
  for (int off = 8; off; off >>= 1) r0 = fmaxf(r0, __shfl_xor(r0, off, 16));
  float e0 = expf(ax - r0), es0 = e0;
  #pragma unroll
  for (int off = 8; off; off >>= 1) es0 += __shfl_xor(es0, off, 16);
  float attx = e0 / es0;

  float am = gmm * tm[h];
  float s2 = am * am;
  #pragma unroll
  for (int off = 8; off; off >>= 1) s2 += __shfl_xor(s2, off, 16);
  am = am / fmaxf(sqrtf(s2), EPSN);
  float r1 = am;
  #pragma unroll
  for (int off = 8; off; off >>= 1) r1 = fmaxf(r1, __shfl_xor(r1, off, 16));
  float e1 = expf(am - r1), es1 = e1;
  #pragma unroll
  for (int off = 8; off; off >>= 1) es1 += __shfl_xor(es1, off, 16);
  float attm = e1 / es1;

  float aa = attx + attm;
  float r2 = aa;
  #pragma unroll
  for (int off = 8; off; off >>= 1) r2 = fmaxf(r2, __shfl_xor(r2, off, 16));
  float e2 = expf(aa - r2), es2 = e2;
  #pragma unroll
  for (int off = 8; off; off >>= 1) es2 += __shfl_xor(es2, off, 16);

  attnbuf[(((size_t)lb * DIM + g) << 8) + t] = e2 / es2;
}

// ---------------- K4: out_blk = attn @ v (bf16), t written bf16 --------------
// grid (64 (hh), 96 (g), nb), block 256
__global__ __launch_bounds__(256) void k_pv(
    const unsigned short* __restrict__ vbuf, const float* __restrict__ attnbuf,
    unsigned short* __restrict__ tout) {
  int hh = blockIdx.x;
  int g = blockIdx.y;
  int lb = blockIdx.z;
  int t = threadIdx.x;
  int ww = t & 63, grp = t >> 6;

  __shared__ float vt[16][64];
  __shared__ float at[16][16];

  const unsigned short* vb = vbuf + ((size_t)lb * DIM + g) * NPIX;
  #pragma unroll
  for (int jj = 0; jj < 4; ++jj) {
    int mm = jj * 4 + grp;
    vt[mm][ww] = bf2f(vb[(size_t)(((mm >> 2) << 6) + hh) * WPIX + ((mm & 3) << 6) + ww]);
  }
  at[t >> 4][t & 15] = attnbuf[(((size_t)lb * DIM + g) << 8) + t];
  __syncthreads();

  unsigned short* ob = tout + ((size_t)lb * DIM + g) * NPIX;
  #pragma unroll
  for (int jj = 0; jj < 4; ++jj) {
    int nn = jj * 4 + grp;
    float acc = 0.f;
    #pragma unroll
    for (int mm = 0; mm < 16; ++mm)
      acc = fmaf(at[nn][mm], vt[mm][ww], acc);
    ob[(size_t)(((nn >> 2) << 6) + hh) * WPIX + ((nn & 3) << 6) + ww] = f2bf(acc);
  }
}

extern "C" void kernel_launch(void* const* d_in, const int* in_sizes, int n_in,
                              void* d_out, int out_size, void* d_ws, size_t ws_size,
                              hipStream_t stream) {
  const float* x      = (const float*)d_in[0];
  const float* mask   = (const float*)d_in[1];
  const float* w_qkv  = (const float*)d_in[2];
  const float* w_dw   = (const float*)d_in[3];
  const float* w_proj = (const float*)d_in[4];
  const float* tx     = (const float*)d_in[5];
  const float* tm     = (const float*)d_in[6];
  float* out = (float*)d_out;

  const size_t wB     = (size_t)(QKVC * DIM + DIM * DIM) * 2;  // 73728
  const size_t qkv1B  = (size_t)QKVC * NPIX * 2;   // 37.75 MB (>= tbuf 12.6 MB bf16)
  const size_t qkB    = (size_t)192 * NPIX * 2;    // 25.2 MB
  const size_t vB     = (size_t)DIM * NPIX * 2;    // 12.6 MB
  const size_t atB    = (size_t)DIM * 256 * 4;
  const size_t pbB    = (size_t)DIM * 16 * PSTRIDE * 4;
  const size_t perB   = qkv1B + qkB + vB + atB + pbB;

  int nb = (ws_size >= wB + 4 * perB) ? 4 : 1;
  int npass = 4 / nb;

  char* base = (char*)d_ws;
  unsigned short* wqbf = (unsigned short*)base;
  unsigned short* wpbf = wqbf + QKVC * DIM;
  char* p = base + wB;
  unsigned short* qkv1bf = (unsigned short*)p;  p += (size_t)nb * qkv1B;
  unsigned short* tbuf   = qkv1bf;              // alias: dead after dw
  unsigned short* qkbuf  = (unsigned short*)p;  p += (size_t)nb * qkB;
  unsigned short* vbuf   = (unsigned short*)p;  p += (size_t)nb * vB;
  float*          attn   = (float*)p;           p += (size_t)nb * atB;
  float*          pbuf   = (float*)p;

  dim3 blk(256);
  k_wprep<<<dim3((QKVC * DIM + 255) / 256), blk, 0, stream>>>(
      w_qkv, w_proj, wqbf, wpbf);

  for (int pass = 0; pass < npass; ++pass) {
    int b0 = pass * nb;
    k_gemm1x1<QKVC, 96, float, unsigned short><<<dim3(NPIX / 128, 3, nb), blk, 0, stream>>>(
        x + (size_t)b0 * DIM * NPIX, wqbf, qkv1bf);
    k_dw3x3_bf<<<dim3(NPIX / 4096, QKVC, nb), blk, 0, stream>>>(
        qkv1bf, w_dw, qkbuf, vbuf);
    k_attn_part<<<dim3(DIM, 16, nb), dim3(64), 0, stream>>>(
        qkbuf, mask + (size_t)b0 * DIM * NPIX, pbuf);
    k_attn_fin<<<dim3(DIM, nb), blk, 0, stream>>>(pbuf, tx, tm, attn);
    k_pv<<<dim3(64, DIM, nb), blk, 0, stream>>>(vbuf, attn, tbuf);
    k_gemm1x1<DIM, 96, unsigned short, float><<<dim3(NPIX / 128, 1, nb), blk, 0, stream>>>(
        tbuf, wpbf, out + (size_t)b0 * DIM * NPIX);
  }
}